// Round 5
// baseline (979.972 us; speedup 1.0000x reference)
//
#include <hip/hip_runtime.h>
#include <math.h>

#define T_TOK 4096
#define H_DIM 1024
#define I_DIM 4096
#define E_NUM 8

// All staged bf16 matrices live in 8KB chunks: [128 rows][32 k] shorts,
// row-major, rows are 64B. gld_lds stages 1KB (16 rows) per instruction,
// fully contiguous in global. Swizzle: byte ^= ((row&3)<<4), applied on the
// gld SOURCE address (LDS dest linear) and again on ds_read (involution).

typedef short s16x8 __attribute__((ext_vector_type(8)));
typedef float f32x4 __attribute__((ext_vector_type(4)));

__device__ __forceinline__ unsigned short f2b(float f) {
  union { float f; unsigned u; } v; v.f = f;
  unsigned r = v.u + 0x7fffu + ((v.u >> 16) & 1u);
  return (unsigned short)(r >> 16);
}

__device__ __forceinline__ void gld_lds16(short* lds, const short* g) {
  __builtin_amdgcn_global_load_lds(
      (const __attribute__((address_space(1))) void*)g,
      (__attribute__((address_space(3))) void*)lds, 16, 0, 0);
}

// Branch-free exact-GELU via A&S 7.1.25 3-term erf (|eps|<=2.5e-5).
__device__ __forceinline__ float gelu_f(float v) {
  float a = fabsf(v);
  float z = a * 0.70710678118f;
  float t = __builtin_amdgcn_rcpf(fmaf(0.47047f, z, 1.0f));
  float p = fmaf(fmaf(0.7478556f, t, -0.0958798f), t, 0.3480242f) * t;
  float e = __expf(-z * z);
  float erf_abs = fmaf(-p, e, 1.0f);
  return fmaf(0.5f * a, erf_abs, 0.5f * v);
}

// ---------- gate: softmax(x @ Wg^T), one wave per token ----------
__global__ __launch_bounds__(256) void gate_kernel(
    const float* __restrict__ x, const float* __restrict__ Wg,
    float* __restrict__ gate)
{
  int t = blockIdx.x * 4 + (threadIdx.x >> 6);
  int lane = threadIdx.x & 63;
  const float* xr = x + (size_t)t * H_DIM;
  float acc[E_NUM];
#pragma unroll
  for (int e = 0; e < E_NUM; ++e) acc[e] = 0.f;
  for (int j = 0; j < H_DIM / 64; ++j) {
    float xv = xr[lane + j * 64];
#pragma unroll
    for (int e = 0; e < E_NUM; ++e)
      acc[e] += xv * Wg[e * H_DIM + lane + j * 64];
  }
#pragma unroll
  for (int e = 0; e < E_NUM; ++e)
    for (int s = 32; s > 0; s >>= 1)
      acc[e] += __shfl_xor(acc[e], s, 64);
  if (lane == 0) {
    float mx = acc[0];
#pragma unroll
    for (int e = 1; e < E_NUM; ++e) mx = fmaxf(mx, acc[e]);
    float sum = 0.f, ex[E_NUM];
#pragma unroll
    for (int e = 0; e < E_NUM; ++e) { ex[e] = expf(acc[e] - mx); sum += ex[e]; }
    float inv = 1.f / sum;
#pragma unroll
    for (int e = 0; e < E_NUM; ++e) gate[t * E_NUM + e] = ex[e] * inv;
  }
}

// ---------- x fp32 -> xb chunks [(t>>7)*32 + (h>>5)][t&127][h&31] ----------
__global__ __launch_bounds__(256) void convert_x_kernel(
    const float* __restrict__ x, short* __restrict__ xb)
{
  int idx = blockIdx.x * 256 + threadIdx.x;     // 524288 total
  int t = idx >> 7;
  int h0 = (idx & 127) << 3;
  const float* src = x + (size_t)t * H_DIM + h0;
  float4 a = *(const float4*)src;
  float4 b = *(const float4*)(src + 4);
  s16x8 v;
  v[0] = f2b(a.x); v[1] = f2b(a.y); v[2] = f2b(a.z); v[3] = f2b(a.w);
  v[4] = f2b(b.x); v[5] = f2b(b.y); v[6] = f2b(b.z); v[7] = f2b(b.w);
  size_t off = ((size_t)((t >> 7) * 32 + (h0 >> 5))) * 4096
             + (size_t)(t & 127) * 32 + (h0 & 31);
  *(s16x8*)(xb + off) = v;
}

// ---------- W1 [E][H][I] -> W1t chunks [((e*32+i128)*32 + kt32)], k = h ----------
__global__ __launch_bounds__(256) void trans_w1_kernel(
    const float* __restrict__ W1, short* __restrict__ W1t)
{
  __shared__ short tile[64][65];            // [h][i]
  const int e = blockIdx.z;
  const int i0 = blockIdx.x * 64, h0 = blockIdx.y * 64;
  const int tid = threadIdx.x, c = tid & 63, r0 = tid >> 6;
  const float* src = W1 + ((size_t)e * H_DIM + h0) * I_DIM + i0;
#pragma unroll
  for (int j = 0; j < 16; ++j) {
    int r = j * 4 + r0;
    tile[r][c] = f2b(src[(size_t)r * I_DIM + c]);
  }
  __syncthreads();
  const int i = tid & 63, kq = tid >> 6;
#pragma unroll
  for (int w = 0; w < 2; ++w) {
    int kcl = kq + w * 4;                    // h-chunk 0..7
    s16x8 v;
#pragma unroll
    for (int j = 0; j < 8; ++j) v[j] = tile[kcl * 8 + j][i];
    size_t off = (((size_t)e * 32 + (i0 >> 7)) * 32 + (h0 >> 5) + (kcl >> 2)) * 4096
               + (size_t)((i0 & 64) + i) * 32 + (kcl & 3) * 8;
    *(s16x8*)(W1t + off) = v;
  }
}

// ---------- W2 [E][I][H] -> W2t chunks [h128*1024 + kt32], k = e*I+i ----------
__global__ __launch_bounds__(256) void trans_w2_kernel(
    const float* __restrict__ W2, short* __restrict__ W2t)
{
  __shared__ short tile[64][65];            // [i][h]
  const int e = blockIdx.z;
  const int i0 = blockIdx.x * 64, h0 = blockIdx.y * 64;
  const int tid = threadIdx.x, c = tid & 63, r0 = tid >> 6;
  const float* src = W2 + ((size_t)e * I_DIM + i0) * H_DIM + h0;
#pragma unroll
  for (int j = 0; j < 16; ++j) {
    int r = j * 4 + r0;
    tile[r][c] = f2b(src[(size_t)r * H_DIM + c]);
  }
  __syncthreads();
  const int h = tid & 63, kq = tid >> 6;
#pragma unroll
  for (int w = 0; w < 2; ++w) {
    int kcl = kq + w * 4;                    // i-chunk 0..7
    s16x8 v;
#pragma unroll
    for (int j = 0; j < 8; ++j) v[j] = tile[kcl * 8 + j][h];
    size_t off = ((size_t)(h0 >> 7) * 1024 + e * 128 + (i0 >> 5) + (kcl >> 2)) * 4096
               + (size_t)((h0 & 64) + h) * 32 + (kcl & 3) * 8;
    *(s16x8*)(W2t + off) = v;
  }
}

// ================= 128x128xBK32 ring-4 GEMM core =================
// 256 threads = 4 waves (2M x 2N); per-wave C = 64 x 64 (16 frags).
// LDS 64 KiB: A ring-4 at [0,16K) shorts, B ring-4 at [16K,32K).
// Per K-step: VMC(8|4|0); barrier; stage(k+3) [4 gld/wave]; 8 ds_read;
// lgkmcnt(0); 16 MFMA. 2 blocks/CU -> two independent barrier domains.
// Ring-4 safety: stage(k+3) issued after BARR(k) (all waves' reads of that
// buffer, last touched interval k-1, retired); drained by VMC before BARR
// at iter k+2 < first re-read at interval k+3. VMC precedes BARR so the
// barrier certifies ALL waves' stage(k) writes are complete.

#define BARR()  __builtin_amdgcn_s_barrier()
#define FENCE() asm volatile("" ::: "memory")
#define LGKM0() do { asm volatile("s_waitcnt lgkmcnt(0)" ::: "memory"); \
                     __builtin_amdgcn_sched_barrier(0); } while (0)
#define VMC(N)  asm volatile("s_waitcnt vmcnt(" #N ")" ::: "memory")
#define PRIO1() __builtin_amdgcn_s_setprio(1)
#define PRIO0() __builtin_amdgcn_s_setprio(0)
#define SCHEDB() __builtin_amdgcn_sched_barrier(0)
#define MF(A, B, C) __builtin_amdgcn_mfma_f32_16x16x32_bf16(A, B, C, 0, 0, 0)

// ---------- GEMM1 (expert-fused): all 8 experts, one ring pipeline ----------
// A = W1t (rows=i), B = xb (rows=t): D row = i. k-step kk in [0,256):
// e = kk>>5, h-tile = kk&31.
__global__ __launch_bounds__(256, 2) void gemm1_kernel(
    const short* __restrict__ xb, const short* __restrict__ W1t,
    const float* __restrict__ b1, const float* __restrict__ gate,
    short* __restrict__ hg)
{
  extern __shared__ short lds[];
  const int bi = blockIdx.x, bt = blockIdx.y;
  const int tid = threadIdx.x, wave = tid >> 6, lane = tid & 63;
  const int wm = wave >> 1, wn = wave & 1;
  const int g = lane >> 4, r16 = lane & 15;

  // stage: wave handles q = wave*2+{0,1} for each of A,B (1KB per gld).
  const int D0 = (wave * 2) * 1024 + lane * 16;
  const int D1 = (wave * 2 + 1) * 1024 + lane * 16;
  const int s0 = (D0 ^ (((D0 >> 6) & 3) << 4)) >> 1;   // swizzled src, shorts
  const int s1 = (D1 ^ (((D1 >> 6) & 3) << 4)) >> 1;
  short* dA0 = lds + (wave * 2) * 512;
  short* dA1 = lds + (wave * 2 + 1) * 512;
  short* dB0 = lds + 16384 + (wave * 2) * 512;
  short* dB1 = lds + 16384 + (wave * 2 + 1) * 512;

  // frag ds_read offset (shorts): row r16, col g*8, same XOR swizzle
  const int rdf = r16 * 32 + ((g << 3) ^ ((r16 & 3) << 3));
  const short* Ah = lds + (wm * 64) * 32;
  const short* Bh = lds + 16384 + (wn * 64) * 32;

  const short* Bw = xb + (size_t)bt * 32 * 4096;

  f32x4 acc[4][4];
#pragma unroll
  for (int i = 0; i < 4; ++i)
#pragma unroll
    for (int j = 0; j < 4; ++j) acc[i][j] = (f32x4){0.f, 0.f, 0.f, 0.f};

#define STAGE1(KK) do { \
    const int _c = ((KK) >> 5) * 1024 + bi * 32 + ((KK) & 31); \
    const short* _sa = W1t + (size_t)_c * 4096; \
    const short* _sb = Bw + (size_t)((KK) & 31) * 4096; \
    const int _o = ((KK) & 3) * 4096; \
    gld_lds16(dA0 + _o, _sa + s0); \
    gld_lds16(dA1 + _o, _sa + s1); \
    gld_lds16(dB0 + _o, _sb + s0); \
    gld_lds16(dB1 + _o, _sb + s1); } while (0)

  STAGE1(0); STAGE1(1); STAGE1(2);

  for (int e = 0; e < E_NUM; ++e) {
#pragma unroll 4
    for (int t32 = 0; t32 < 32; ++t32) {
      const int k = e * 32 + t32;
      if (k < 254) { VMC(8); } else if (k == 254) { VMC(4); } else { VMC(0); }
      BARR(); FENCE();
      if (k + 3 < 256) STAGE1(k + 3);
      const int o = (k & 3) * 4096;
      s16x8 av[4], bv[4];
#pragma unroll
      for (int mi = 0; mi < 4; ++mi)
        av[mi] = *(const s16x8*)(Ah + o + mi * 512 + rdf);
#pragma unroll
      for (int ni = 0; ni < 4; ++ni)
        bv[ni] = *(const s16x8*)(Bh + o + ni * 512 + rdf);
      LGKM0();
      PRIO1();
#pragma unroll
      for (int mi = 0; mi < 4; ++mi)
#pragma unroll
        for (int ni = 0; ni < 4; ++ni)
          acc[mi][ni] = MF(av[mi], bv[ni], acc[mi][ni]);
      PRIO0(); SCHEDB();
    }

    // per-expert epilogue: gelu(acc+b1)*gate -> hg chunks; reset acc.
    // Global stores join the vmcnt FIFO; the next VMC over-drains (safe).
#pragma unroll
    for (int mi = 0; mi < 4; ++mi) {
      const int i4 = bi * 128 + wm * 64 + mi * 16 + g * 4;  // 4 consecutive i
      const float4 b1v = *(const float4*)(b1 + e * I_DIM + i4);
      const int kt32 = (e * I_DIM + i4) >> 5;
      const int col = i4 & 31;
      short* dst = hg + ((size_t)bt * 1024 + kt32) * 4096 + col;
#pragma unroll
      for (int ni = 0; ni < 4; ++ni) {
        const int tl = wn * 64 + ni * 16 + r16;             // t within tile
        const float gt = gate[(bt * 128 + tl) * E_NUM + e];
        const float v0 = gelu_f(acc[mi][ni][0] + b1v.x) * gt;
        const float v1 = gelu_f(acc[mi][ni][1] + b1v.y) * gt;
        const float v2 = gelu_f(acc[mi][ni][2] + b1v.z) * gt;
        const float v3 = gelu_f(acc[mi][ni][3] + b1v.w) * gt;
        int2 pk;
        pk.x = (int)((unsigned)f2b(v0) | ((unsigned)f2b(v1) << 16));
        pk.y = (int)((unsigned)f2b(v2) | ((unsigned)f2b(v3) << 16));
        *(int2*)(dst + (size_t)tl * 32) = pk;
        acc[mi][ni] = (f32x4){0.f, 0.f, 0.f, 0.f};
      }
    }
  }
#undef STAGE1
}

// ---------- GEMM2: part[ks] = hg-tile @ W2-tile (split-K=2) ----------
// A = W2t (rows=h), B = hg (rows=t): D row = h (float4 stores).
__global__ __launch_bounds__(256, 2) void gemm2_kernel(
    const short* __restrict__ W2t, const short* __restrict__ hg,
    float* __restrict__ part)
{
  extern __shared__ short lds[];
  const int bh = blockIdx.x, bt = blockIdx.y, ks = blockIdx.z;
  const int tid = threadIdx.x, wave = tid >> 6, lane = tid & 63;
  const int wm = wave >> 1, wn = wave & 1;
  const int g = lane >> 4, r16 = lane & 15;

  const int D0 = (wave * 2) * 1024 + lane * 16;
  const int D1 = (wave * 2 + 1) * 1024 + lane * 16;
  const int s0 = (D0 ^ (((D0 >> 6) & 3) << 4)) >> 1;
  const int s1 = (D1 ^ (((D1 >> 6) & 3) << 4)) >> 1;
  short* dA0 = lds + (wave * 2) * 512;
  short* dA1 = lds + (wave * 2 + 1) * 512;
  short* dB0 = lds + 16384 + (wave * 2) * 512;
  short* dB1 = lds + 16384 + (wave * 2 + 1) * 512;

  const int rdf = r16 * 32 + ((g << 3) ^ ((r16 & 3) << 3));
  const short* Ah = lds + (wm * 64) * 32;
  const short* Bh = lds + 16384 + (wn * 64) * 32;

  const short* Aw = W2t + ((size_t)bh * 1024 + ks * 512) * 4096;
  const short* Bw = hg + ((size_t)bt * 1024 + ks * 512) * 4096;

  f32x4 acc[4][4];
#pragma unroll
  for (int i = 0; i < 4; ++i)
#pragma unroll
    for (int j = 0; j < 4; ++j) acc[i][j] = (f32x4){0.f, 0.f, 0.f, 0.f};

#define STAGE2(KK) do { \
    const short* _sa = Aw + (size_t)(KK) * 4096; \
    const short* _sb = Bw + (size_t)(KK) * 4096; \
    const int _o = ((KK) & 3) * 4096; \
    gld_lds16(dA0 + _o, _sa + s0); \
    gld_lds16(dA1 + _o, _sa + s1); \
    gld_lds16(dB0 + _o, _sb + s0); \
    gld_lds16(dB1 + _o, _sb + s1); } while (0)

  STAGE2(0); STAGE2(1); STAGE2(2);

#pragma unroll 4
  for (int k = 0; k < 512; ++k) {
    if (k < 510) { VMC(8); } else if (k == 510) { VMC(4); } else { VMC(0); }
    BARR(); FENCE();
    if (k + 3 < 512) STAGE2(k + 3);
    const int o = (k & 3) * 4096;
    s16x8 av[4], bv[4];
#pragma unroll
    for (int mi = 0; mi < 4; ++mi)
      av[mi] = *(const s16x8*)(Ah + o + mi * 512 + rdf);
#pragma unroll
    for (int ni = 0; ni < 4; ++ni)
      bv[ni] = *(const s16x8*)(Bh + o + ni * 512 + rdf);
    LGKM0();
    PRIO1();
#pragma unroll
    for (int mi = 0; mi < 4; ++mi)
#pragma unroll
      for (int ni = 0; ni < 4; ++ni)
        acc[mi][ni] = MF(av[mi], bv[ni], acc[mi][ni]);
    PRIO0(); SCHEDB();
  }
#undef STAGE2

  float* dst = part + (size_t)ks * ((size_t)T_TOK * H_DIM);
#pragma unroll
  for (int mi = 0; mi < 4; ++mi) {
    const int h4 = bh * 128 + wm * 64 + mi * 16 + g * 4;    // 4 consecutive h
#pragma unroll
    for (int ni = 0; ni < 4; ++ni) {
      const int t = bt * 128 + wn * 64 + ni * 16 + r16;
      *(f32x4*)(dst + (size_t)t * H_DIM + h4) = acc[mi][ni];
    }
  }
}

// ---------- reduce: out = part0 + part1 + sum_e gate*b2 ----------
__global__ __launch_bounds__(256) void reduce_kernel(
    const float* __restrict__ part, const float* __restrict__ gate,
    const float* __restrict__ b2, float* __restrict__ out)
{
  const int idx = blockIdx.x * 256 + threadIdx.x;   // 1M threads, float4 each
  const int t = idx >> 8;
  const int h4 = (idx & 255) << 2;
  const size_t off = (size_t)t * H_DIM + h4;
  const size_t SL = (size_t)T_TOK * H_DIM;
  float4 a0 = *(const float4*)(part + off);
  float4 a1 = *(const float4*)(part + SL + off);
  float sx = a0.x + a1.x;
  float sy = a0.y + a1.y;
  float sz = a0.z + a1.z;
  float sw = a0.w + a1.w;
#pragma unroll
  for (int e = 0; e < E_NUM; ++e) {
    const float gv = gate[t * E_NUM + e];
    const float4 bv = *(const float4*)(b2 + e * H_DIM + h4);
    sx = fmaf(gv, bv.x, sx); sy = fmaf(gv, bv.y, sy);
    sz = fmaf(gv, bv.z, sz); sw = fmaf(gv, bv.w, sw);
  }
  float4 r; r.x = sx; r.y = sy; r.z = sz; r.w = sw;
  *(float4*)(out + off) = r;
}

// ---------- launch ----------
extern "C" void kernel_launch(void* const* d_in, const int* in_sizes, int n_in,
                              void* d_out, int out_size, void* d_ws, size_t ws_size,
                              hipStream_t stream) {
  const float* x  = (const float*)d_in[0];
  const float* Wg = (const float*)d_in[1];
  const float* W1 = (const float*)d_in[2];
  const float* b1 = (const float*)d_in[3];
  const float* W2 = (const float*)d_in[4];
  const float* b2 = (const float*)d_in[5];
  float* out = (float*)d_out;

  char* ws = (char*)d_ws;
  float* gate = (float*)ws;                                    // 128 KiB
  short* xb   = (short*)(ws + 131072);                         // 8 MiB
  short* W1t  = (short*)(ws + 131072 + 8388608);               // 64 MiB
  short* W2t  = (short*)(ws + 131072 + 8388608 + 67108864);    // 64 MiB
  short* hg   = (short*)(ws + 131072 + 8388608 + 2 * 67108864);// 256 MiB
  // part aliases xb+W1t (both dead after gemm1): 2 x 16 MiB
  float* part = (float*)(ws + 131072);

  static bool attr_done = false;
  if (!attr_done) {
    hipFuncSetAttribute((const void*)gemm1_kernel,
                        hipFuncAttributeMaxDynamicSharedMemorySize, 65536);
    hipFuncSetAttribute((const void*)gemm2_kernel,
                        hipFuncAttributeMaxDynamicSharedMemorySize, 65536);
    attr_done = true;
  }

  gate_kernel<<<T_TOK / 4, 256, 0, stream>>>(x, Wg, gate);
  convert_x_kernel<<<2048, 256, 0, stream>>>(x, xb);
  trans_w1_kernel<<<dim3(I_DIM / 64, H_DIM / 64, E_NUM), 256, 0, stream>>>(W1, W1t);
  trans_w2_kernel<<<dim3(I_DIM / 64, H_DIM / 64, E_NUM), 256, 0, stream>>>(W2, W2t);
  gemm1_kernel<<<dim3(32, 32), 256, 65536, stream>>>(xb, W1t, b1, gate, hg);
  gemm2_kernel<<<dim3(8, 32, 2), 256, 65536, stream>>>(W2t, hg, part);
  reduce_kernel<<<4096, 256, 0, stream>>>(part, gate, b2, out);
}